// Round 4
// baseline (74.457 us; speedup 1.0000x reference)
//
#include <hip/hip_runtime.h>
#include <math.h>

// Tropical (min-plus) matmul: out[b,o] = min_j (x[b,j] + w[o,j])
// x: [512, 512] f32, w: [1024, 512] f32, out: [512, 1024] f32
//
// R3 post-mortem: kernel ~32us vs 3.4us VALU floor. Suspects: DS-inst
// throughput (0.25 DS/MAC, ~12cyc/inst shared per CU) + unroll-8 VGPR
// pressure + 4-way w-read bank conflicts.
// R4: 4x4 strided thread tile -> 0.125 DS/MAC (8 b128 per 4j = 64 MACs),
// all LDS reads <=2-way conflicts (rows t+16s, PADW=68), unroll 2.
// Grid stays 512 (2 blocks/CU) via k-split=4 (block tile 64x64, K=128)
// + combine kernel (min over 4 partials in d_ws, ~8MB traffic).

typedef float v2f __attribute__((ext_vector_type(2)));

#define B_    512
#define IN_   512
#define OUT_  1024
#define TBB   64    // b rows per block
#define TOO   64    // o cols per block
#define BK    64    // k chunk
#define NCHUNK 2    // chunks per block (K=128 per k-slice)
#define KSPLIT 4
#define PADW  68    // 272B row stride: %16==0 (b128-aligned), stride-1 rows
                    // step banks by 4 -> 16 rows hit 8 bank-groups (2-way, free)

__global__ __launch_bounds__(256, 2) void tropical_main(
    const float* __restrict__ x, const float* __restrict__ w,
    float* __restrict__ part)
{
    __shared__ float xs[TBB * PADW];   // xs[row][j]
    __shared__ float ws[TOO * PADW];   // ws[row][j]

    const int tid = threadIdx.x;
    const int b0 = blockIdx.x * TBB;   // 8 tiles
    const int o0 = blockIdx.y * TOO;   // 16 tiles
    const int kz = blockIdx.z;         // 4 k-slices
    const int kbase = kz * (BK * NCHUNK);

    // staging: 64 rows x 16 float4 cols per tile, 4 rows/thread
    const int scol = tid & 15;
    const int srow = tid >> 4;

    // compute: strided 4x4 tile. rows tb+16s (x), cols to+16s (w).
    // In-wave: x reads 4 unique rows (16-way bcast), w 16 unique (4-way bcast).
    const int to = tid & 15;
    const int tb = tid >> 4;

    float acc[4][4];
#pragma unroll
    for (int i = 0; i < 4; ++i)
#pragma unroll
        for (int o = 0; o < 4; ++o)
            acc[i][o] = INFINITY;

    for (int c = 0; c < NCHUNK; ++c) {
        const int jc = kbase + c * BK;
        // ---- stage x tile (64 x 64 floats), coalesced float4 ----
#pragma unroll
        for (int p = 0; p < 4; ++p) {
            const int r = srow + p * 16;
            const float4 v = *(const float4*)&x[(size_t)(b0 + r) * IN_ + jc + scol * 4];
            *(float4*)&xs[r * PADW + scol * 4] = v;
        }
        // ---- stage w tile ----
#pragma unroll
        for (int p = 0; p < 4; ++p) {
            const int r = srow + p * 16;
            const float4 v = *(const float4*)&w[(size_t)(o0 + r) * IN_ + jc + scol * 4];
            *(float4*)&ws[r * PADW + scol * 4] = v;
        }
        __syncthreads();

        // ---- main loop: per 4j, 8x ds_read_b128 -> 64 MACs (1.0 VALU/MAC) ----
#pragma unroll 2
        for (int j = 0; j < BK; j += 4) {
            float4 xv[4], wv[4];
#pragma unroll
            for (int s = 0; s < 4; ++s)
                xv[s] = *(const float4*)&xs[(tb + 16 * s) * PADW + j];
#pragma unroll
            for (int s = 0; s < 4; ++s)
                wv[s] = *(const float4*)&ws[(to + 16 * s) * PADW + j];
#pragma unroll
            for (int i = 0; i < 4; ++i)
#pragma unroll
                for (int o = 0; o < 4; ++o) {
                    v2f t0 = (v2f){xv[i].x, xv[i].y} + (v2f){wv[o].x, wv[o].y};
                    v2f t1 = (v2f){xv[i].z, xv[i].w} + (v2f){wv[o].z, wv[o].w};
                    acc[i][o] = fminf(fminf(acc[i][o], t0.x), t0.y);  // v_min3
                    acc[i][o] = fminf(fminf(acc[i][o], t1.x), t1.y);
                }
        }
        __syncthreads();
    }

    // ---- epilogue: partial mins to d_ws slice kz ----
    float* p = part + (size_t)kz * B_ * OUT_;
#pragma unroll
    for (int i = 0; i < 4; ++i) {
        const int row = b0 + tb + 16 * i;
#pragma unroll
        for (int o = 0; o < 4; ++o)
            p[(size_t)row * OUT_ + o0 + to + 16 * o] = acc[i][o];
    }
}

__global__ __launch_bounds__(256) void tropical_combine(
    const float* __restrict__ part, float* __restrict__ out)
{
    const int idx = (blockIdx.x * 256 + threadIdx.x) * 4;
    const size_t N = (size_t)B_ * OUT_;
    float4 a = *(const float4*)&part[idx];
#pragma unroll
    for (int z = 1; z < KSPLIT; ++z) {
        const float4 b = *(const float4*)&part[z * N + idx];
        a.x = fminf(a.x, b.x);
        a.y = fminf(a.y, b.y);
        a.z = fminf(a.z, b.z);
        a.w = fminf(a.w, b.w);
    }
    *(float4*)&out[idx] = a;
}

extern "C" void kernel_launch(void* const* d_in, const int* in_sizes, int n_in,
                              void* d_out, int out_size, void* d_ws, size_t ws_size,
                              hipStream_t stream) {
    const float* x = (const float*)d_in[0];   // [512, 512]
    const float* w = (const float*)d_in[1];   // [1024, 512]
    float* out = (float*)d_out;               // [512, 1024]
    float* part = (float*)d_ws;               // 4 x 512 x 1024 f32 = 8 MB

    dim3 grid(B_ / TBB, OUT_ / TOO, KSPLIT);  // 8 x 16 x 4 = 512 blocks
    tropical_main<<<grid, 256, 0, stream>>>(x, w, part);

    const int nvec = (B_ * OUT_) / 4;         // 131072 float4s
    tropical_combine<<<nvec / 256, 256, 0, stream>>>(part, out);
}